// Round 1
// baseline (426.488 us; speedup 1.0000x reference)
//
#include <hip/hip_runtime.h>

#define D_ 256
#define K_ 1024
#define HW_ 1024
#define NROWS_ 32768
#define QELEMS 8388608  // 32*256*32*32

// ---------------- prep: transpose emb -> emb_t[D][K], enorm[k] = sum e^2, zero counts/loss
__global__ __launch_bounds__(256) void vq_prep(const float* __restrict__ emb,
    float* __restrict__ emb_t, float* __restrict__ enorm,
    int* __restrict__ counts, double* __restrict__ loss_acc)
{
    int k = blockIdx.x, t = threadIdx.x;           // k in [0,1024), t in [0,256)
    float v = emb[k * D_ + t];
    emb_t[t * K_ + k] = v;
    float s = v * v;
    for (int o = 32; o > 0; o >>= 1) s += __shfl_down(s, o);
    __shared__ float ws4[4];
    if ((t & 63) == 0) ws4[t >> 6] = s;
    __syncthreads();
    if (t == 0) enorm[k] = ws4[0] + ws4[1] + ws4[2] + ws4[3];
    if (k < 4) counts[k * 256 + t] = 0;
    if (k == 0 && t == 0) *loss_acc = 0.0;
}

// ---------------- main: per 32-row tile, fp32 GEMM vs all codes, top-2 + fp64 refine, loss
__global__ __launch_bounds__(256) void vq_main(
    const float* __restrict__ x, const float* __restrict__ emb,
    const float* __restrict__ emb_t, const float* __restrict__ enorm,
    int* __restrict__ idx, int* __restrict__ counts, double* __restrict__ loss_acc)
{
    __shared__ float xt[D_][32];          // 32 KB: xt[d][r]
    __shared__ float rv1[32][33], rv2[32][33];
    __shared__ int   ri1[32][33], ri2[32][33];
    __shared__ int   idxsh[32];
    __shared__ float lred[4];

    const int t = threadIdx.x;
    const int n0 = blockIdx.x * 32;
    const int b = n0 >> 10;
    const int hw0 = n0 & 1023;
    const float* xbase = x + (size_t)b * (D_ * HW_) + hw0;
    {
        int r = t & 31, dq = t >> 5;
        for (int d = dq; d < D_; d += 8)
            xt[d][r] = xbase[(size_t)d * HW_ + r];
    }
    __syncthreads();

    const int rg = t & 7, kg = t >> 3;    // rows 4*rg..4*rg+3 ; codes kg*4.. per pass
    float v1[4], v2[4]; int i1[4], i2[4];
#pragma unroll
    for (int i = 0; i < 4; ++i) { v1[i] = v2[i] = 3.4e38f; i1[i] = i2[i] = 0x7fffffff; }

    for (int pass = 0; pass < 8; ++pass) {
        const int kbase = pass * 128 + kg * 4;
        float acc[4][4];
#pragma unroll
        for (int i = 0; i < 4; ++i)
#pragma unroll
            for (int j = 0; j < 4; ++j) acc[i][j] = 0.f;
        const float4* ep = (const float4*)(emb_t + kbase);
        const float4* xp = (const float4*)(&xt[0][rg * 4]);
#pragma unroll 4
        for (int d = 0; d < D_; ++d) {
            float4 xv = xp[(size_t)d * 8];        // xt[d][4rg..4rg+3]
            float4 ev = ep[(size_t)d * (K_ / 4)]; // emb_t[d][kbase..kbase+3]
            acc[0][0] = fmaf(xv.x, ev.x, acc[0][0]);
            acc[0][1] = fmaf(xv.x, ev.y, acc[0][1]);
            acc[0][2] = fmaf(xv.x, ev.z, acc[0][2]);
            acc[0][3] = fmaf(xv.x, ev.w, acc[0][3]);
            acc[1][0] = fmaf(xv.y, ev.x, acc[1][0]);
            acc[1][1] = fmaf(xv.y, ev.y, acc[1][1]);
            acc[1][2] = fmaf(xv.y, ev.z, acc[1][2]);
            acc[1][3] = fmaf(xv.y, ev.w, acc[1][3]);
            acc[2][0] = fmaf(xv.z, ev.x, acc[2][0]);
            acc[2][1] = fmaf(xv.z, ev.y, acc[2][1]);
            acc[2][2] = fmaf(xv.z, ev.z, acc[2][2]);
            acc[2][3] = fmaf(xv.z, ev.w, acc[2][3]);
            acc[3][0] = fmaf(xv.w, ev.x, acc[3][0]);
            acc[3][1] = fmaf(xv.w, ev.y, acc[3][1]);
            acc[3][2] = fmaf(xv.w, ev.z, acc[3][2]);
            acc[3][3] = fmaf(xv.w, ev.w, acc[3][3]);
        }
#pragma unroll
        for (int j = 0; j < 4; ++j) {
            float bn = enorm[kbase + j];
            int kk = kbase + j;
#pragma unroll
            for (int i = 0; i < 4; ++i) {
                float bv = fmaf(-2.f, acc[i][j], bn);
                if (bv < v1[i]) { v2[i] = v1[i]; i2[i] = i1[i]; v1[i] = bv; i1[i] = kk; }
                else if (bv < v2[i]) { v2[i] = bv; i2[i] = kk; }
            }
        }
    }
#pragma unroll
    for (int i = 0; i < 4; ++i) {
        int row = rg * 4 + i;
        rv1[row][kg] = v1[i]; ri1[row][kg] = i1[i];
        rv2[row][kg] = v2[i]; ri2[row][kg] = i2[i];
    }
    __syncthreads();

    if (t < 32) {
        float bv1 = 3.4e38f, bv2 = 3.4e38f; int bi1 = 0x7fffffff, bi2 = 0x7fffffff;
        for (int g = 0; g < 32; ++g) {
            float c1 = rv1[t][g]; int ci1 = ri1[t][g];
            float c2 = rv2[t][g]; int ci2 = ri2[t][g];
            if (c1 < bv1 || (c1 == bv1 && ci1 < bi1)) { bv2 = bv1; bi2 = bi1; bv1 = c1; bi1 = ci1; }
            else if (c1 < bv2 || (c1 == bv2 && ci1 < bi2)) { bv2 = c1; bi2 = ci1; }
            if (c2 < bv1 || (c2 == bv1 && ci2 < bi1)) { bv2 = bv1; bi2 = bi1; bv1 = c2; bi1 = ci2; }
            else if (c2 < bv2 || (c2 == bv2 && ci2 < bi2)) { bv2 = c2; bi2 = ci2; }
        }
        int best = bi1;
        if (bv2 - bv1 < 4e-6f) {
            // fp64 re-resolution of the near-tie (rare: ~20 rows total)
            double d1 = 0.0, d2 = 0.0;
            const float* e1 = emb + (size_t)bi1 * D_;
            const float* e2 = emb + (size_t)bi2 * D_;
            for (int d = 0; d < D_; ++d) {
                double xv = (double)xt[d][t];
                double a = (double)e1[d];
                double c = (double)e2[d];
                d1 += a * (a - 2.0 * xv);
                d2 += c * (c - 2.0 * xv);
            }
            if (d2 < d1 || (d2 == d1 && bi2 < bi1)) best = bi2;
        }
        idxsh[t] = best;
        idx[n0 + t] = best;
        atomicAdd(&counts[best], 1);
    }
    __syncthreads();

    // loss partial: sum over tile of (emb[idx][d] - x)^2
    {
        int r = t & 31, dq = t >> 5;
        const float* erow = emb + (size_t)idxsh[r] * D_;
        float ls = 0.f;
#pragma unroll 4
        for (int dd = 0; dd < 32; ++dd) {
            int d = dq * 32 + dd;
            float diff = erow[d] - xt[d][r];
            ls = fmaf(diff, diff, ls);
        }
        for (int o = 32; o > 0; o >>= 1) ls += __shfl_down(ls, o);
        if ((t & 63) == 0) lred[t >> 6] = ls;
        __syncthreads();
        if (t == 0) atomicAdd(loss_acc, (double)(lred[0] + lred[1] + lred[2] + lred[3]));
    }
}

// ---------------- scatter quantized (BCHW): out[b][d][hw] = emb[idx[b*1024+hw]][d]
__global__ __launch_bounds__(256) void vq_scatter(const float* __restrict__ emb,
    const int* __restrict__ idx, float* __restrict__ outq)
{
    size_t m = (size_t)blockIdx.x * 256 + threadIdx.x;
    int hw = (int)(m & 1023);
    int d = (int)((m >> 10) & 255);
    int b = (int)(m >> 18);
    int n = (b << 10) + hw;
    outq[m] = emb[(size_t)idx[n] * D_ + d];
}

// ---------------- one-hot encodings [N][K] as float2
__global__ __launch_bounds__(256) void vq_enc(const int* __restrict__ idx,
    float2* __restrict__ enc)
{
    size_t m = (size_t)blockIdx.x * 256 + threadIdx.x; // N*K/2 total
    int n = (int)(m >> 9);
    int k2 = (int)(m & 511) << 1;
    int kk = idx[n];
    float2 v;
    v.x = (kk == k2) ? 1.f : 0.f;
    v.y = (kk == k2 + 1) ? 1.f : 0.f;
    enc[m] = v;
}

// ---------------- finalize: loss scalar + perplexity
__global__ __launch_bounds__(256) void vq_fin(const int* __restrict__ counts,
    const double* __restrict__ loss_acc, float* __restrict__ d_out)
{
    int t = threadIdx.x;
    double s = 0.0;
    for (int k = t; k < K_; k += 256) {
        double p = (double)counts[k] / 32768.0;
        s += p * log(p + 1e-10);
    }
    for (int o = 32; o > 0; o >>= 1) s += __shfl_down(s, o);
    __shared__ double sred[4];
    if ((t & 63) == 0) sred[t >> 6] = s;
    __syncthreads();
    if (t == 0) {
        double tot = sred[0] + sred[1] + sred[2] + sred[3];
        d_out[0] = (float)(1.25 * (*loss_acc) / (double)QELEMS);
        d_out[8388609] = (float)exp(-tot);
    }
}

extern "C" void kernel_launch(void* const* d_in, const int* in_sizes, int n_in,
                              void* d_out, int out_size, void* d_ws, size_t ws_size,
                              hipStream_t stream)
{
    const float* x = (const float*)d_in[0];
    const float* emb = (const float*)d_in[1];
    char* ws = (char*)d_ws;
    float* emb_t = (float*)(ws);                                   // 1 MB
    float* enorm = (float*)(ws + 1048576);                         // 4 KB
    int* idx = (int*)(ws + 1048576 + 4096);                        // 128 KB
    int* counts = (int*)(ws + 1048576 + 4096 + 131072);            // 4 KB
    double* lacc = (double*)(ws + 1048576 + 4096 + 131072 + 4096); // 8 B
    float* out = (float*)d_out;

    vq_prep<<<K_, 256, 0, stream>>>(emb, emb_t, enorm, counts, lacc);
    vq_main<<<NROWS_ / 32, 256, 0, stream>>>(x, emb, emb_t, enorm, idx, counts, lacc);
    vq_scatter<<<QELEMS / 256, 256, 0, stream>>>(emb, idx, out + 1);
    vq_enc<<<(NROWS_ * (K_ / 2)) / 256, 256, 0, stream>>>(idx, (float2*)(out + 8388610));
    vq_fin<<<1, 256, 0, stream>>>(counts, lacc, out);
}

// Round 4
// 166.981 us; speedup vs baseline: 2.5541x; 2.5541x over previous
//
#include <hip/hip_runtime.h>
#include <hip/hip_bf16.h>

typedef short short8 __attribute__((ext_vector_type(8)));
typedef float f32x4 __attribute__((ext_vector_type(4)));

#define D_ 256
#define K_ 1024
#define HW_ 1024
#define NROWS_ 32768
#define QELEMS 8388608  // 32*256*32*32
#define TH_REFINE 1e-3f

// ---------------- prep: emb -> bf16 codebook ebf[k][d], enorm[k]=sum e^2, zero counts/loss
__global__ __launch_bounds__(256) void vq_prep(const float* __restrict__ emb,
    unsigned short* __restrict__ ebf, float* __restrict__ enorm,
    int* __restrict__ counts, double* __restrict__ loss_acc)
{
    int k = blockIdx.x, t = threadIdx.x;           // k in [0,1024), t in [0,256)
    float v = emb[k * D_ + t];
    __hip_bfloat16 h = __float2bfloat16(v);
    ebf[k * D_ + t] = *(unsigned short*)&h;
    float s = v * v;
    for (int o = 32; o > 0; o >>= 1) s += __shfl_down(s, o);
    __shared__ float ws4[4];
    if ((t & 63) == 0) ws4[t >> 6] = s;
    __syncthreads();
    if (t == 0) enorm[k] = ws4[0] + ws4[1] + ws4[2] + ws4[3];
    if (k < 4) counts[k * 256 + t] = 0;
    if (k == 0 && t == 0) *loss_acc = 0.0;
}

// ---------------- main: 64 rows/block, bf16 MFMA vs all 1024 codes, top-2 + fp64 refine, loss
__global__ __launch_bounds__(256, 2) void vq_main(
    const float* __restrict__ x, const float* __restrict__ emb,
    const unsigned short* __restrict__ ebf, const float* __restrict__ enorm,
    int* __restrict__ idx, int* __restrict__ counts, double* __restrict__ loss_acc)
{
    __shared__ unsigned short xs[64 * 256];   // 32KB, XOR-swizzled rows
    __shared__ float rv1[64][33];
    __shared__ float rv2[64][33];
    __shared__ int   ri1[64][33];
    __shared__ int   ri2[64][33];
    __shared__ int   idxsh[64];
    __shared__ float lred[4];

    const int t = threadIdx.x;
    const int n0 = blockIdx.x * 64;
    const int b = n0 >> 10;
    const int hw0 = n0 & 1023;
    const float* xbase = x + (size_t)b * (D_ * HW_) + hw0;

    // ---- stage x -> bf16 LDS (transpose d-major -> row-major, swizzled)
    {
        int r = t & 63;
        int dq = t >> 6;   // 0..3
        for (int i = 0; i < 64; ++i) {
            int d = dq * 64 + i;
            float v = xbase[(size_t)d * HW_ + r];
            __hip_bfloat16 h = __float2bfloat16(v);
            int addr = ((r * 512 + d * 2) ^ ((r & 7) << 4)) >> 1;  // short index
            xs[addr] = *(unsigned short*)&h;
        }
    }
    __syncthreads();

    const int lane = t & 63;
    const int w = t >> 6;          // wave 0..3
    const int rh = w & 1;          // row half (32 rows)
    const int ch = w >> 1;         // code half (32 of each 64-chunk)
    const int col = lane & 15;
    const int kg = lane >> 4;      // k-group 0..3

    // ---- preload all A fragments (x rows) into registers: 2 rowtiles x 8 d-chunks
    short8 areg[2][8];
#pragma unroll
    for (int rt = 0; rt < 2; ++rt) {
        int row = rh * 32 + rt * 16 + col;
        int rowb = row * 512;
        int sw = (row & 7) << 4;
#pragma unroll
        for (int dc = 0; dc < 8; ++dc) {
            int addr = ((rowb + dc * 64 + kg * 16) ^ sw) >> 1;
            areg[rt][dc] = *(const short8*)&xs[addr];
        }
    }

    float v1[8], v2[8]; int i1[8], i2[8];
#pragma unroll
    for (int s = 0; s < 8; ++s) { v1[s] = v2[s] = 3.4e38f; i1[s] = i2[s] = 0x7fffffff; }

    for (int cc = 0; cc < 16; ++cc) {
        const int cbase = cc * 64 + ch * 32;
        f32x4 acc[2][2];
#pragma unroll
        for (int rt = 0; rt < 2; ++rt)
#pragma unroll
            for (int ct = 0; ct < 2; ++ct) { f32x4 z = {0.f,0.f,0.f,0.f}; acc[rt][ct] = z; }

#pragma unroll
        for (int dc = 0; dc < 8; ++dc) {
            // B fragments straight from global (L2-resident bf16 codebook)
            short8 b0 = *(const short8*)(ebf + ((size_t)(cbase + col) << 8) + dc * 32 + kg * 8);
            short8 b1 = *(const short8*)(ebf + ((size_t)(cbase + 16 + col) << 8) + dc * 32 + kg * 8);
            acc[0][0] = __builtin_amdgcn_mfma_f32_16x16x32_bf16(areg[0][dc], b0, acc[0][0], 0, 0, 0);
            acc[0][1] = __builtin_amdgcn_mfma_f32_16x16x32_bf16(areg[0][dc], b1, acc[0][1], 0, 0, 0);
            acc[1][0] = __builtin_amdgcn_mfma_f32_16x16x32_bf16(areg[1][dc], b0, acc[1][0], 0, 0, 0);
            acc[1][1] = __builtin_amdgcn_mfma_f32_16x16x32_bf16(areg[1][dc], b1, acc[1][1], 0, 0, 0);
        }
        // epilogue: dist = enorm - 2*dot ; C/D map: row=(lane>>4)*4+reg, col=lane&15
#pragma unroll
        for (int ct = 0; ct < 2; ++ct) {
            int code = cbase + ct * 16 + col;
            float bn = enorm[code];
#pragma unroll
            for (int rt = 0; rt < 2; ++rt) {
#pragma unroll
                for (int r = 0; r < 4; ++r) {
                    float dv = fmaf(-2.f, acc[rt][ct][r], bn);
                    int s = rt * 4 + r;
                    if (dv < v1[s]) { v2[s]=v1[s]; i2[s]=i1[s]; v1[s]=dv; i1[s]=code; }
                    else if (dv < v2[s]) { v2[s]=dv; i2[s]=code; }
                }
            }
        }
    }

    // ---- per-lane top2 -> LDS (row owned by lanes with same kg; 16 cols x 2 code-halves)
#pragma unroll
    for (int s = 0; s < 8; ++s) {
        int rt = s >> 2, r = s & 3;
        int row = rh * 32 + rt * 16 + kg * 4 + r;
        int slot = col + 16 * ch;
        rv1[row][slot] = v1[s]; ri1[row][slot] = i1[s];
        rv2[row][slot] = v2[s]; ri2[row][slot] = i2[s];
    }
    __syncthreads();

    if (t < 64) {
        float bv1 = 3.4e38f, bv2 = 3.4e38f; int bi1 = 0x7fffffff, bi2 = 0x7fffffff;
        for (int g = 0; g < 32; ++g) {
            float c1 = rv1[t][g]; int ci1 = ri1[t][g];
            float c2 = rv2[t][g]; int ci2 = ri2[t][g];
            if (c1 < bv1 || (c1 == bv1 && ci1 < bi1)) { bv2=bv1; bi2=bi1; bv1=c1; bi1=ci1; }
            else if (c1 < bv2 || (c1 == bv2 && ci1 < bi2)) { bv2=c1; bi2=ci1; }
            if (c2 < bv1 || (c2 == bv1 && ci2 < bi1)) { bv2=bv1; bi2=bi1; bv1=c2; bi1=ci2; }
            else if (c2 < bv2 || (c2 == bv2 && ci2 < bi2)) { bv2=c2; bi2=ci2; }
        }
        int best = bi1;
        if (bv2 - bv1 < TH_REFINE) {
            // fp64 re-resolution of near-tie using fp32 x from global (rare)
            const float* xr = x + (size_t)b * (D_ * HW_) + (hw0 + t);
            const float* e1 = emb + (size_t)bi1 * D_;
            const float* e2 = emb + (size_t)bi2 * D_;
            double d1 = 0.0, d2 = 0.0;
            for (int d = 0; d < D_; ++d) {
                double xv = (double)xr[(size_t)d * HW_];
                double a = (double)e1[d], c = (double)e2[d];
                d1 += a * (a - 2.0 * xv);
                d2 += c * (c - 2.0 * xv);
            }
            if (d2 < d1 || (d2 == d1 && bi2 < bi1)) best = bi2;
        }
        idxsh[t] = best;
        idx[n0 + t] = best;
        atomicAdd(&counts[best], 1);
    }
    __syncthreads();

    // ---- loss partial: sum (emb[idx][d] - x)^2 using bf16 x from LDS (bias ~1e-6 rel)
    {
        int r = t & 63, dq = t >> 6;
        const float* erow = emb + (size_t)idxsh[r] * D_;
        int sw = (r & 7) << 4;
        float ls = 0.f;
#pragma unroll
        for (int i = 0; i < 8; ++i) {
            int d0 = dq * 64 + i * 8;
            int addr = ((r * 512 + d0 * 2) ^ sw) >> 1;
            short8 xv = *(const short8*)&xs[addr];
#pragma unroll
            for (int j = 0; j < 8; ++j) {
                unsigned int ui = ((unsigned int)(unsigned short)xv[j]) << 16;
                float xf = __builtin_bit_cast(float, ui);
                float diff = erow[d0 + j] - xf;
                ls = fmaf(diff, diff, ls);
            }
        }
        for (int o = 32; o > 0; o >>= 1) ls += __shfl_down(ls, o);
        if ((t & 63) == 0) lred[t >> 6] = ls;
        __syncthreads();
        if (t == 0) atomicAdd(loss_acc, (double)(lred[0]+lred[1]+lred[2]+lred[3]));
    }
}

// ---------------- scatter quantized (BCHW): out[b][d][hw] = emb[idx[b*1024+hw]][d]
__global__ __launch_bounds__(256) void vq_scatter(const float* __restrict__ emb,
    const int* __restrict__ idx, float* __restrict__ outq)
{
    size_t m = (size_t)blockIdx.x * 256 + threadIdx.x;
    int hw = (int)(m & 1023);
    int d = (int)((m >> 10) & 255);
    int b = (int)(m >> 18);
    int n = (b << 10) + hw;
    outq[m] = emb[(size_t)idx[n] * D_ + d];
}

// ---------------- one-hot encodings [N][K] as float2
__global__ __launch_bounds__(256) void vq_enc(const int* __restrict__ idx,
    float2* __restrict__ enc)
{
    size_t m = (size_t)blockIdx.x * 256 + threadIdx.x; // N*K/2 total
    int n = (int)(m >> 9);
    int k2 = (int)(m & 511) << 1;
    int kk = idx[n];
    float2 v;
    v.x = (kk == k2) ? 1.f : 0.f;
    v.y = (kk == k2 + 1) ? 1.f : 0.f;
    enc[m] = v;
}

// ---------------- finalize: loss scalar + perplexity
__global__ __launch_bounds__(256) void vq_fin(const int* __restrict__ counts,
    const double* __restrict__ loss_acc, float* __restrict__ d_out)
{
    int t = threadIdx.x;
    double s = 0.0;
    for (int k = t; k < K_; k += 256) {
        double p = (double)counts[k] / 32768.0;
        s += p * log(p + 1e-10);
    }
    for (int o = 32; o > 0; o >>= 1) s += __shfl_down(s, o);
    __shared__ double sred[4];
    if ((t & 63) == 0) sred[t >> 6] = s;
    __syncthreads();
    if (t == 0) {
        double tot = sred[0] + sred[1] + sred[2] + sred[3];
        d_out[0] = (float)(1.25 * (*loss_acc) / (double)QELEMS);
        d_out[8388609] = (float)exp(-tot);
    }
}

extern "C" void kernel_launch(void* const* d_in, const int* in_sizes, int n_in,
                              void* d_out, int out_size, void* d_ws, size_t ws_size,
                              hipStream_t stream)
{
    const float* x = (const float*)d_in[0];
    const float* emb = (const float*)d_in[1];
    char* ws = (char*)d_ws;
    unsigned short* ebf = (unsigned short*)(ws);                 // 512 KB
    float* enorm = (float*)(ws + 524288);                        // 4 KB
    int* idx = (int*)(ws + 528384);                              // 128 KB
    int* counts = (int*)(ws + 659456);                           // 4 KB
    double* lacc = (double*)(ws + 663552);                       // 8 B
    float* out = (float*)d_out;

    vq_prep<<<K_, 256, 0, stream>>>(emb, ebf, enorm, counts, lacc);
    vq_main<<<NROWS_ / 64, 256, 0, stream>>>(x, emb, ebf, enorm, idx, counts, lacc);
    vq_scatter<<<QELEMS / 256, 256, 0, stream>>>(emb, idx, out + 1);
    vq_enc<<<(NROWS_ * (K_ / 2)) / 256, 256, 0, stream>>>(idx, (float2*)(out + 8388610));
    vq_fin<<<1, 256, 0, stream>>>(counts, lacc, out);
}